// Round 1
// 474.617 us; speedup vs baseline: 1.0002x; 1.0002x over previous
//
#include <hip/hip_runtime.h>
#include <hip/hip_fp16.h>

#define E_N 80000
#define T_N 80000
#define NB1 313   // ceil(80000/256) blocks for scan kernels

typedef _Float16 h4 __attribute__((ext_vector_type(4)));
typedef _Float16 h8 __attribute__((ext_vector_type(8)));
typedef float    f4 __attribute__((ext_vector_type(4)));
typedef float    f2 __attribute__((ext_vector_type(2)));

static __device__ __forceinline__ float swishf(float x) {
    return x / (1.0f + __expf(-x));
}

// ---------------------------------------------------------------------------
// Fused weight packing (one launch instead of four).
// kp_pack body (W_bil, validated R1) : blocks [0,128)
// kpack_w (W_down 256x64, NT=4)      : blocks [128,136)
// kpack_w (W_t1   294x64, NT=4, pad) : blocks [136,146)
// kpack_w (W_up    64x256, NT=16)    : blocks [146,154)
// ---------------------------------------------------------------------------
static __device__ __forceinline__ void pack_w_dev(const float* __restrict__ src,
                                                  h8* __restrict__ dst,
                                                  int g, int Ksrc, int N, int NT) {
    int lane = g & 63, frag = g >> 6;
    int nt = frag % NT, kt = frag / NT;
    int quad = (lane >> 4);
    int n = nt * 16 + (lane & 15);
    int k0 = kt * 32 + quad * 8;
    h8 v;
#pragma unroll
    for (int u = 0; u < 8; ++u) {
        int k = k0 + u;
        v[u] = (k < Ksrc) ? (_Float16)src[(size_t)k * N + n] : (_Float16)0.0f;
    }
    dst[g] = v;
}

__global__ __launch_bounds__(256) void kpack_all(const float* __restrict__ Wb,  h8* __restrict__ wbil,
                                                 const float* __restrict__ Wd,  h8* __restrict__ wpd,
                                                 const float* __restrict__ Wt,  h8* __restrict__ wpt,
                                                 const float* __restrict__ Wu,  h8* __restrict__ wpu) {
    int b = blockIdx.x, tid = threadIdx.x;
    if (b < 128) {
        int g = b * 256 + tid;                      // 0..32767
        int i    = ((g >> 6) & 3) * 16 + (g & 15);
        int c    = (g >> 8) & 1;
        int j    = g >> 9;
        int quad = (g >> 4) & 3;
        int l0   = c * 32 + quad * 8;
        const float* src = Wb + ((i * 64 + j) << 6) + l0;
        h8 v;
#pragma unroll
        for (int u = 0; u < 8; ++u) v[u] = (_Float16)src[u];
        wbil[g] = v;
    } else if (b < 136) {
        pack_w_dev(Wd, wpd, (b - 128) * 256 + tid, 256, 64, 4);
    } else if (b < 146) {
        pack_w_dev(Wt, wpt, (b - 136) * 256 + tid, 294, 64, 4);
    } else {
        pack_w_dev(Wu, wpu, (b - 146) * 256 + tid, 64, 256, 16);
    }
}

// ---------------------------------------------------------------------------
// K1 (MFMA): xke = f16( swish( (x_kj * rbf) @ W_down ) )
// ---------------------------------------------------------------------------
__global__ __launch_bounds__(256, 4) void k1_down(const float* __restrict__ rbf0,
                                                  const float* __restrict__ xkj,
                                                  const float* __restrict__ W_rbf1,
                                                  const float* __restrict__ W_rbf2,
                                                  const h8* __restrict__ wpd,
                                                  _Float16* __restrict__ xke) {
    int tid = threadIdx.x;
    int lane = tid & 63, wv = tid >> 6;
    int m = lane & 15, quad = lane >> 4;
    int rowb = blockIdx.x * 128 + wv * 32;

    float r8[2][8];
#pragma unroll
    for (int rt = 0; rt < 2; ++rt) {
        int r = rowb + rt * 16 + m;
        float rv[6];
#pragma unroll
        for (int q = 0; q < 6; ++q) rv[q] = rbf0[(size_t)r * 6 + q];
#pragma unroll
        for (int p = 0; p < 8; ++p) {
            float s = 0.f;
#pragma unroll
            for (int q = 0; q < 6; ++q) s += rv[q] * W_rbf1[q * 8 + p];
            r8[rt][p] = s;
        }
    }

    f4 acc[2][4] = {};
#pragma unroll
    for (int kb = 0; kb < 8; ++kb) {
        int k0 = kb * 32 + quad * 8;
        h8 afrag[2];
#pragma unroll
        for (int rt = 0; rt < 2; ++rt) {
            f4 rlo = {}, rhi = {};
#pragma unroll
            for (int p = 0; p < 8; ++p) {
                rlo += r8[rt][p] * *(const f4*)(W_rbf2 + p * 256 + k0);
                rhi += r8[rt][p] * *(const f4*)(W_rbf2 + p * 256 + k0 + 4);
            }
            size_t base = (size_t)(rowb + rt * 16 + m) * 256 + k0;
            f4 xlo = *(const f4*)(xkj + base);
            f4 xhi = *(const f4*)(xkj + base + 4);
            rlo *= xlo; rhi *= xhi;
            h8 a;
#pragma unroll
            for (int u = 0; u < 4; ++u) {
                a[u]     = (_Float16)rlo[u];
                a[u + 4] = (_Float16)rhi[u];
            }
            afrag[rt] = a;
        }
#pragma unroll
        for (int nt = 0; nt < 4; ++nt) {
            h8 b = wpd[((kb * 4 + nt) << 6) + lane];
            acc[0][nt] = __builtin_amdgcn_mfma_f32_16x16x32_f16(afrag[0], b, acc[0][nt], 0, 0, 0);
            acc[1][nt] = __builtin_amdgcn_mfma_f32_16x16x32_f16(afrag[1], b, acc[1][nt], 0, 0, 0);
        }
    }

#pragma unroll
    for (int rt = 0; rt < 2; ++rt)
#pragma unroll
        for (int nt = 0; nt < 4; ++nt)
#pragma unroll
            for (int rr = 0; rr < 4; ++rr) {
                int row = rowb + rt * 16 + quad * 4 + rr;
                xke[(size_t)row * 64 + nt * 16 + m] = (_Float16)swishf(acc[rt][nt][rr]);
            }
}

// ---------------------------------------------------------------------------
// KB1 (MFMA): tt = f16( t @ W_t1 ). K=294 padded to 320, N=64.
// ---------------------------------------------------------------------------
__global__ __launch_bounds__(256) void kb1_tproj(const float* __restrict__ tin,
                                                 const h8* __restrict__ wpt,
                                                 _Float16* __restrict__ ttb) {
    int tid = threadIdx.x;
    int lane = tid & 63, wv = tid >> 6;
    int m = lane & 15, quad = lane >> 4;
    int rowb = blockIdx.x * 128 + wv * 32;

    f4 acc[2][4] = {};
    for (int ktg = 0; ktg < 10; ++ktg) {
        int k0 = ktg * 32 + quad * 8;
        h8 afrag[2];
#pragma unroll
        for (int rt = 0; rt < 2; ++rt) {
            size_t base = (size_t)(rowb + rt * 16 + m) * 294 + k0;
            h8 a;
            if (k0 + 8 <= 294) {
                f2 t0 = *(const f2*)(tin + base);
                f2 t1 = *(const f2*)(tin + base + 2);
                f2 t2 = *(const f2*)(tin + base + 4);
                f2 t3 = *(const f2*)(tin + base + 6);
                a[0] = (_Float16)t0[0]; a[1] = (_Float16)t0[1];
                a[2] = (_Float16)t1[0]; a[3] = (_Float16)t1[1];
                a[4] = (_Float16)t2[0]; a[5] = (_Float16)t2[1];
                a[6] = (_Float16)t3[0]; a[7] = (_Float16)t3[1];
            } else {
#pragma unroll
                for (int u = 0; u < 8; ++u) {
                    int k = k0 + u;
                    a[u] = (k < 294) ? (_Float16)tin[base + u] : (_Float16)0.0f;
                }
            }
            afrag[rt] = a;
        }
#pragma unroll
        for (int nt = 0; nt < 4; ++nt) {
            h8 b = wpt[((ktg * 4 + nt) << 6) + lane];
#pragma unroll
            for (int rt = 0; rt < 2; ++rt)
                acc[rt][nt] = __builtin_amdgcn_mfma_f32_16x16x32_f16(afrag[rt], b, acc[rt][nt], 0, 0, 0);
        }
    }

#pragma unroll
    for (int rt = 0; rt < 2; ++rt)
#pragma unroll
        for (int nt = 0; nt < 4; ++nt)
#pragma unroll
            for (int rr = 0; rr < 4; ++rr) {
                int row = rowb + rt * 16 + quad * 4 + rr;
                ttb[(size_t)row * 64 + nt * 16 + m] = (_Float16)acc[rt][nt][rr];
            }
}

// ---------------------------------------------------------------------------
// KB2: xkt[w] = xke[idx_kj[w]] * ((sbf@W_sbf1)@W_sbf2)[w]   (f16 out)
// Also builds hist[e] = #triplets with idx_ji==e (folded in to save a launch).
// ---------------------------------------------------------------------------
__global__ __launch_bounds__(256) void kb2_gather(const float* __restrict__ sbf,
                                                  const float* __restrict__ W_sbf1,
                                                  const float* __restrict__ W_sbf2,
                                                  const _Float16* __restrict__ xke,
                                                  const int* __restrict__ idx_kj,
                                                  const int* __restrict__ idx_ji,
                                                  int* __restrict__ hist,
                                                  _Float16* __restrict__ xkt) {
    __shared__ float sbfL[32 * 42];
    __shared__ float midL[32 * 8];
    int tid = threadIdx.x;
    int row0 = blockIdx.x * 32;
    if (tid < 32) atomicAdd(&hist[idx_ji[row0 + tid]], 1);
    for (int i = tid; i < 32 * 42; i += 256)
        sbfL[i] = sbf[(size_t)row0 * 42 + i];
    __syncthreads();
    {
        int r = tid >> 3, p = tid & 7;
        float mm = 0.f;
#pragma unroll
        for (int q = 0; q < 42; ++q) mm += sbfL[r * 42 + q] * W_sbf1[q * 8 + p];
        midL[r * 8 + p] = mm;
    }
    __syncthreads();
    int r = tid >> 3;
    int c0 = (tid & 7) * 8;
    int w = row0 + r;
    int e = idx_kj[w];
    f4 sa = {}, sb = {};
#pragma unroll
    for (int p = 0; p < 8; ++p) {
        float mm = midL[r * 8 + p];
        sa += mm * *(const f4*)(W_sbf2 + (p << 6) + c0);
        sb += mm * *(const f4*)(W_sbf2 + (p << 6) + c0 + 4);
    }
    h8 xv = *(const h8*)(xke + (size_t)e * 64 + c0);
    h8 o;
#pragma unroll
    for (int u = 0; u < 4; ++u) {
        o[u]     = (_Float16)((float)xv[u]     * sa[u]);
        o[u + 4] = (_Float16)((float)xv[u + 4] * sb[u]);
    }
    *(h8*)(xkt + (size_t)w * 64 + c0) = o;
}

// ---------------------------------------------------------------------------
// CSR placement chain: hist -> block sums -> offsets -> start/next -> pos
// pos[w] = sorted slot for triplet w (grouped by idx_ji). ~6us total.
// ---------------------------------------------------------------------------
__global__ __launch_bounds__(256) void kscan1(const int* __restrict__ hist, int* __restrict__ bsum) {
    int t = threadIdx.x;
    int w = blockIdx.x * 256 + t;
    int v = (w < E_N) ? hist[w] : 0;
#pragma unroll
    for (int off = 32; off; off >>= 1) v += __shfl_down(v, off, 64);
    __shared__ int ls[4];
    if ((t & 63) == 0) ls[t >> 6] = v;
    __syncthreads();
    if (t == 0) bsum[blockIdx.x] = ls[0] + ls[1] + ls[2] + ls[3];
}

__global__ __launch_bounds__(512) void kscan2(const int* __restrict__ bsum, int* __restrict__ boff) {
    __shared__ int s[512];
    int t = threadIdx.x;
    int v = (t < NB1) ? bsum[t] : 0;
    s[t] = v;
    __syncthreads();
    for (int off = 1; off < 512; off <<= 1) {
        int x = (t >= off) ? s[t - off] : 0;
        __syncthreads();
        s[t] += x;
        __syncthreads();
    }
    if (t < NB1) boff[t] = s[t] - v;   // exclusive
}

__global__ __launch_bounds__(256) void kscan3(const int* __restrict__ hist, const int* __restrict__ boff,
                                              int* __restrict__ start, int* __restrict__ nxt) {
    __shared__ int s[256];
    int t = threadIdx.x;
    int w = blockIdx.x * 256 + t;
    int v = (w < E_N) ? hist[w] : 0;
    s[t] = v;
    __syncthreads();
    for (int off = 1; off < 256; off <<= 1) {
        int x = (t >= off) ? s[t - off] : 0;
        __syncthreads();
        s[t] += x;
        __syncthreads();
    }
    if (w < E_N) {
        int st = boff[blockIdx.x] + s[t] - v;
        start[w] = st;
        nxt[w]   = st;
    }
}

__global__ __launch_bounds__(256) void kfill(const int* __restrict__ idx_ji,
                                             int* __restrict__ nxt, int* __restrict__ pos) {
    int w = blockIdx.x * 256 + threadIdx.x;
    if (w < T_N) pos[w] = atomicAdd(&nxt[idx_ji[w]], 1);
}

// ---------------------------------------------------------------------------
// KB3: bilinear, zero-LDS, ZERO-ATOMIC epilogue. Identical compute to prior
// version; instead of 10.24M random f32 atomicAdds (L2-line bouncing across
// XCDs was 63% of pipeline time), each partial row is STORED to its sorted
// slot pos[w] in outp (two j-half buffers). Each store instr covers 4 full
// 64B lines. Aggregation happens in kagg as a streaming segment-sum.
// ---------------------------------------------------------------------------
__global__ __launch_bounds__(128, 3) void kb3_bilinear(const _Float16* __restrict__ xkt,
                                                       const _Float16* __restrict__ ttp,
                                                       const h8* __restrict__ wpack,
                                                       const int* __restrict__ pos,
                                                       float* __restrict__ outp) {
    int tid = threadIdx.x;
    int lane = tid & 63, wv = tid >> 6;
    int qrow = lane & 15, quad = lane >> 4;
    int row0 = blockIdx.x * 128 + wv * 64;
    int jlo = blockIdx.y * 32;

    h8 xa[4][2];
#pragma unroll
    for (int rt = 0; rt < 4; ++rt) {
        const _Float16* rp = xkt + (size_t)(row0 + rt * 16 + qrow) * 64 + quad * 8;
        xa[rt][0] = *(const h8*)rp;
        xa[rt][1] = *(const h8*)(rp + 32);
    }

    f4 acc[4][4] = {};
#pragma unroll
    for (int jg = 0; jg < 4; ++jg) {
        h8 tg[4];
#pragma unroll
        for (int rt = 0; rt < 4; ++rt)
            tg[rt] = *(const h8*)(ttp + (size_t)(row0 + rt * 16 + qrow) * 64 + jlo + jg * 8);
#pragma unroll
        for (int ju = 0; ju < 8; ++ju) {
            int j = jlo + jg * 8 + ju;
            const h8* wj = wpack + (((size_t)j * 8) << 6) + lane;
            h8 b0[4], b1[4];
#pragma unroll
            for (int nt = 0; nt < 4; ++nt) {
                b0[nt] = wj[nt << 6];         // c=0
                b1[nt] = wj[(4 + nt) << 6];   // c=1
            }
#pragma unroll
            for (int rt = 0; rt < 4; ++rt) {
                _Float16 tv = tg[rt][ju];
                h8 t8 = {tv, tv, tv, tv, tv, tv, tv, tv};
                h8 a0 = xa[rt][0] * t8;
                h8 a1 = xa[rt][1] * t8;
#pragma unroll
                for (int nt = 0; nt < 4; ++nt) {
                    acc[rt][nt] = __builtin_amdgcn_mfma_f32_16x16x32_f16(a0, b0[nt], acc[rt][nt], 0, 0, 0);
                    acc[rt][nt] = __builtin_amdgcn_mfma_f32_16x16x32_f16(a1, b1[nt], acc[rt][nt], 0, 0, 0);
                }
            }
        }
    }

    // C/D layout: col = lane&15, row = quad*4 + reg  (verified m89/m91)
    float* __restrict__ outh = outp + (size_t)blockIdx.y * ((size_t)T_N * 64);
#pragma unroll
    for (int rt = 0; rt < 4; ++rt) {
#pragma unroll
        for (int rr = 0; rr < 4; ++rr) {
            int w = row0 + rt * 16 + quad * 4 + rr;
            float* dst = outh + (size_t)pos[w] * 64 + qrow;
#pragma unroll
            for (int nt = 0; nt < 4; ++nt)
                dst[nt * 16] = acc[rt][nt][rr];
        }
    }
}

// ---------------------------------------------------------------------------
// KAGG: agg[e,:] = sum over the contiguous sorted range of edge e's triplets,
// both j-half buffers. 16 lanes per edge (f4 each) -> fully coalesced 256B
// row reads, coalesced writes. Replaces the agg memset too.
// ---------------------------------------------------------------------------
__global__ __launch_bounds__(256) void kagg(const float* __restrict__ outp,
                                            const int* __restrict__ start,
                                            const int* __restrict__ nxt,
                                            float* __restrict__ agg) {
    int tid = threadIdx.x;
    int e = blockIdx.x * 16 + (tid >> 4);
    int c4 = (tid & 15) * 4;
    int p0 = start[e], p1 = nxt[e];
    const float* o1 = outp + (size_t)T_N * 64;
    f4 s = {0.f, 0.f, 0.f, 0.f};
    for (int p = p0; p < p1; ++p) {
        s += *(const f4*)(outp + (size_t)p * 64 + c4);
        s += *(const f4*)(o1   + (size_t)p * 64 + c4);
    }
    *(f4*)(agg + (size_t)e * 64 + c4) = s;
}

// ---------------------------------------------------------------------------
// K4 (MFMA): out = swish( agg @ W_up ). K=64 (2 kt), N=256 (16 nt).
// ---------------------------------------------------------------------------
__global__ __launch_bounds__(256) void k4_up(const float* __restrict__ agg,
                                             const h8* __restrict__ wpu,
                                             float* __restrict__ out) {
    int tid = threadIdx.x;
    int lane = tid & 63, wv = tid >> 6;
    int m = lane & 15, quad = lane >> 4;
    int rowb = blockIdx.x * 64 + wv * 16;

    f4 acc[16] = {};
#pragma unroll
    for (int kt = 0; kt < 2; ++kt) {
        const float* ap = agg + (size_t)(rowb + m) * 64 + kt * 32 + quad * 8;
        f4 alo = *(const f4*)ap;
        f4 ahi = *(const f4*)(ap + 4);
        h8 a;
#pragma unroll
        for (int u = 0; u < 4; ++u) {
            a[u]     = (_Float16)alo[u];
            a[u + 4] = (_Float16)ahi[u];
        }
#pragma unroll
        for (int nt = 0; nt < 16; ++nt) {
            h8 b = wpu[((kt * 16 + nt) << 6) + lane];
            acc[nt] = __builtin_amdgcn_mfma_f32_16x16x32_f16(a, b, acc[nt], 0, 0, 0);
        }
    }

#pragma unroll
    for (int nt = 0; nt < 16; ++nt)
#pragma unroll
        for (int rr = 0; rr < 4; ++rr) {
            int row = rowb + quad * 4 + rr;
            out[(size_t)row * 256 + nt * 16 + m] = swishf(acc[nt][rr]);
        }
}

// ---------------------------------------------------------------------------
extern "C" void kernel_launch(void* const* d_in, const int* in_sizes, int n_in,
                              void* d_out, int out_size, void* d_ws, size_t ws_size,
                              hipStream_t stream) {
    const float* rbf0   = (const float*)d_in[1];
    const float* sbf    = (const float*)d_in[2];
    const float* tin    = (const float*)d_in[3];
    const float* xkj    = (const float*)d_in[4];
    const int*   idx_kj = (const int*)d_in[6];
    const int*   idx_ji = (const int*)d_in[7];
    const float* W_rbf1 = (const float*)d_in[8];
    const float* W_rbf2 = (const float*)d_in[9];
    const float* W_sbf1 = (const float*)d_in[10];
    const float* W_sbf2 = (const float*)d_in[11];
    const float* W_t1   = (const float*)d_in[12];
    const float* W_down = (const float*)d_in[13];
    const float* W_up   = (const float*)d_in[14];
    const float* W_bil  = (const float*)d_in[15];

    // ws: xke 10.24MB | agg 20.48MB | wpack_bil 512KB | wpd 32KB | wpt 40KB | wpu 32KB
    char* ws = (char*)d_ws;
    _Float16* xke = (_Float16*)ws;
    float*    agg = (float*)(ws + 10240000);
    h8* wpack_bil = (h8*)(ws + 30720000);
    h8* wpd       = (h8*)(ws + 31244288);
    h8* wpt       = (h8*)(ws + 31277056);
    h8* wpu       = (h8*)(ws + 31318016);

    // d_out scratch (81.92MB total; everything dead before k4_up overwrites):
    // ttb 10.24 | xkt 10.24 | outp 40.96 (2 j-half partial buffers) | CSR ints
    char* ob = (char*)d_out;
    _Float16* ttb  = (_Float16*)ob;
    _Float16* xkt  = (_Float16*)(ob + 10240000);
    float*    outp = (float*)(ob + 20480000);
    int* hist  = (int*)(ob + 61440000);   // 320KB
    int* start = (int*)(ob + 61760000);   // 320KB
    int* nxt   = (int*)(ob + 62080000);   // 320KB
    int* pos   = (int*)(ob + 62400000);   // 320KB
    int* bsum  = (int*)(ob + 62720000);   // 1252B (pad 4KB)
    int* boff  = (int*)(ob + 62724096);   // 1252B
    float* out = (float*)d_out;

    hipMemsetAsync(hist, 0, E_N * 4, stream);
    kpack_all<<<154, 256, 0, stream>>>(W_bil, wpack_bil, W_down, wpd, W_t1, wpt, W_up, wpu);
    k1_down<<<625, 256, 0, stream>>>(rbf0, xkj, W_rbf1, W_rbf2, wpd, xke);
    kb1_tproj<<<625, 256, 0, stream>>>(tin, wpt, ttb);
    kb2_gather<<<2500, 256, 0, stream>>>(sbf, W_sbf1, W_sbf2, xke, idx_kj, idx_ji, hist, xkt);
    kscan1<<<NB1, 256, 0, stream>>>(hist, bsum);
    kscan2<<<1, 512, 0, stream>>>(bsum, boff);
    kscan3<<<NB1, 256, 0, stream>>>(hist, boff, start, nxt);
    kfill<<<NB1, 256, 0, stream>>>(idx_ji, nxt, pos);
    kb3_bilinear<<<dim3(625, 2), 128, 0, stream>>>(xkt, ttb, wpack_bil, pos, outp);
    kagg<<<5000, 256, 0, stream>>>(outp, start, nxt, agg);
    k4_up<<<1250, 256, 0, stream>>>(agg, wpu, out);
}

// Round 3
// 468.008 us; speedup vs baseline: 1.0143x; 1.0141x over previous
//
#include <hip/hip_runtime.h>
#include <hip/hip_fp16.h>

#define E_N 80000
#define T_N 80000
#define NB1 313   // ceil(80000/256) blocks for scan kernels

typedef _Float16 h4 __attribute__((ext_vector_type(4)));
typedef _Float16 h8 __attribute__((ext_vector_type(8)));
typedef float    f4 __attribute__((ext_vector_type(4)));
typedef float    f2 __attribute__((ext_vector_type(2)));

static __device__ __forceinline__ float swishf(float x) {
    return x / (1.0f + __expf(-x));
}

// ---------------------------------------------------------------------------
// Fused weight packing (one launch instead of four).
// ---------------------------------------------------------------------------
static __device__ __forceinline__ void pack_w_dev(const float* __restrict__ src,
                                                  h8* __restrict__ dst,
                                                  int g, int Ksrc, int N, int NT) {
    int lane = g & 63, frag = g >> 6;
    int nt = frag % NT, kt = frag / NT;
    int quad = (lane >> 4);
    int n = nt * 16 + (lane & 15);
    int k0 = kt * 32 + quad * 8;
    h8 v;
#pragma unroll
    for (int u = 0; u < 8; ++u) {
        int k = k0 + u;
        v[u] = (k < Ksrc) ? (_Float16)src[(size_t)k * N + n] : (_Float16)0.0f;
    }
    dst[g] = v;
}

__global__ __launch_bounds__(256) void kpack_all(const float* __restrict__ Wb,  h8* __restrict__ wbil,
                                                 const float* __restrict__ Wd,  h8* __restrict__ wpd,
                                                 const float* __restrict__ Wt,  h8* __restrict__ wpt,
                                                 const float* __restrict__ Wu,  h8* __restrict__ wpu) {
    int b = blockIdx.x, tid = threadIdx.x;
    if (b < 128) {
        int g = b * 256 + tid;                      // 0..32767
        int i    = ((g >> 6) & 3) * 16 + (g & 15);
        int c    = (g >> 8) & 1;
        int j    = g >> 9;
        int quad = (g >> 4) & 3;
        int l0   = c * 32 + quad * 8;
        const float* src = Wb + ((i * 64 + j) << 6) + l0;
        h8 v;
#pragma unroll
        for (int u = 0; u < 8; ++u) v[u] = (_Float16)src[u];
        wbil[g] = v;
    } else if (b < 136) {
        pack_w_dev(Wd, wpd, (b - 128) * 256 + tid, 256, 64, 4);
    } else if (b < 146) {
        pack_w_dev(Wt, wpt, (b - 136) * 256 + tid, 294, 64, 4);
    } else {
        pack_w_dev(Wu, wpu, (b - 146) * 256 + tid, 64, 256, 16);
    }
}

// ---------------------------------------------------------------------------
// K1 (MFMA): xke = f16( swish( (x_kj * rbf) @ W_down ) )
// ---------------------------------------------------------------------------
__global__ __launch_bounds__(256, 4) void k1_down(const float* __restrict__ rbf0,
                                                  const float* __restrict__ xkj,
                                                  const float* __restrict__ W_rbf1,
                                                  const float* __restrict__ W_rbf2,
                                                  const h8* __restrict__ wpd,
                                                  _Float16* __restrict__ xke) {
    int tid = threadIdx.x;
    int lane = tid & 63, wv = tid >> 6;
    int m = lane & 15, quad = lane >> 4;
    int rowb = blockIdx.x * 128 + wv * 32;

    float r8[2][8];
#pragma unroll
    for (int rt = 0; rt < 2; ++rt) {
        int r = rowb + rt * 16 + m;
        float rv[6];
#pragma unroll
        for (int q = 0; q < 6; ++q) rv[q] = rbf0[(size_t)r * 6 + q];
#pragma unroll
        for (int p = 0; p < 8; ++p) {
            float s = 0.f;
#pragma unroll
            for (int q = 0; q < 6; ++q) s += rv[q] * W_rbf1[q * 8 + p];
            r8[rt][p] = s;
        }
    }

    f4 acc[2][4] = {};
#pragma unroll
    for (int kb = 0; kb < 8; ++kb) {
        int k0 = kb * 32 + quad * 8;
        h8 afrag[2];
#pragma unroll
        for (int rt = 0; rt < 2; ++rt) {
            f4 rlo = {}, rhi = {};
#pragma unroll
            for (int p = 0; p < 8; ++p) {
                rlo += r8[rt][p] * *(const f4*)(W_rbf2 + p * 256 + k0);
                rhi += r8[rt][p] * *(const f4*)(W_rbf2 + p * 256 + k0 + 4);
            }
            size_t base = (size_t)(rowb + rt * 16 + m) * 256 + k0;
            f4 xlo = *(const f4*)(xkj + base);
            f4 xhi = *(const f4*)(xkj + base + 4);
            rlo *= xlo; rhi *= xhi;
            h8 a;
#pragma unroll
            for (int u = 0; u < 4; ++u) {
                a[u]     = (_Float16)rlo[u];
                a[u + 4] = (_Float16)rhi[u];
            }
            afrag[rt] = a;
        }
#pragma unroll
        for (int nt = 0; nt < 4; ++nt) {
            h8 b = wpd[((kb * 4 + nt) << 6) + lane];
            acc[0][nt] = __builtin_amdgcn_mfma_f32_16x16x32_f16(afrag[0], b, acc[0][nt], 0, 0, 0);
            acc[1][nt] = __builtin_amdgcn_mfma_f32_16x16x32_f16(afrag[1], b, acc[1][nt], 0, 0, 0);
        }
    }

#pragma unroll
    for (int rt = 0; rt < 2; ++rt)
#pragma unroll
        for (int nt = 0; nt < 4; ++nt)
#pragma unroll
            for (int rr = 0; rr < 4; ++rr) {
                int row = rowb + rt * 16 + quad * 4 + rr;
                xke[(size_t)row * 64 + nt * 16 + m] = (_Float16)swishf(acc[rt][nt][rr]);
            }
}

// ---------------------------------------------------------------------------
// KB1 (MFMA): tt = f16( t @ W_t1 ). K=294 padded to 320, N=64.
// ---------------------------------------------------------------------------
__global__ __launch_bounds__(256) void kb1_tproj(const float* __restrict__ tin,
                                                 const h8* __restrict__ wpt,
                                                 _Float16* __restrict__ ttb) {
    int tid = threadIdx.x;
    int lane = tid & 63, wv = tid >> 6;
    int m = lane & 15, quad = lane >> 4;
    int rowb = blockIdx.x * 128 + wv * 32;

    f4 acc[2][4] = {};
    for (int ktg = 0; ktg < 10; ++ktg) {
        int k0 = ktg * 32 + quad * 8;
        h8 afrag[2];
#pragma unroll
        for (int rt = 0; rt < 2; ++rt) {
            size_t base = (size_t)(rowb + rt * 16 + m) * 294 + k0;
            h8 a;
            if (k0 + 8 <= 294) {
                f2 t0 = *(const f2*)(tin + base);
                f2 t1 = *(const f2*)(tin + base + 2);
                f2 t2 = *(const f2*)(tin + base + 4);
                f2 t3 = *(const f2*)(tin + base + 6);
                a[0] = (_Float16)t0[0]; a[1] = (_Float16)t0[1];
                a[2] = (_Float16)t1[0]; a[3] = (_Float16)t1[1];
                a[4] = (_Float16)t2[0]; a[5] = (_Float16)t2[1];
                a[6] = (_Float16)t3[0]; a[7] = (_Float16)t3[1];
            } else {
#pragma unroll
                for (int u = 0; u < 8; ++u) {
                    int k = k0 + u;
                    a[u] = (k < 294) ? (_Float16)tin[base + u] : (_Float16)0.0f;
                }
            }
            afrag[rt] = a;
        }
#pragma unroll
        for (int nt = 0; nt < 4; ++nt) {
            h8 b = wpt[((ktg * 4 + nt) << 6) + lane];
#pragma unroll
            for (int rt = 0; rt < 2; ++rt)
                acc[rt][nt] = __builtin_amdgcn_mfma_f32_16x16x32_f16(afrag[rt], b, acc[rt][nt], 0, 0, 0);
        }
    }

#pragma unroll
    for (int rt = 0; rt < 2; ++rt)
#pragma unroll
        for (int nt = 0; nt < 4; ++nt)
#pragma unroll
            for (int rr = 0; rr < 4; ++rr) {
                int row = rowb + rt * 16 + quad * 4 + rr;
                ttb[(size_t)row * 64 + nt * 16 + m] = (_Float16)acc[rt][nt][rr];
            }
}

// ---------------------------------------------------------------------------
// KB2: xkt[w] = xke[idx_kj[w]] * ((sbf@W_sbf1)@W_sbf2)[w]   (f16 out)
// Also builds hist[e] = #triplets with idx_ji==e.
// ---------------------------------------------------------------------------
__global__ __launch_bounds__(256) void kb2_gather(const float* __restrict__ sbf,
                                                  const float* __restrict__ W_sbf1,
                                                  const float* __restrict__ W_sbf2,
                                                  const _Float16* __restrict__ xke,
                                                  const int* __restrict__ idx_kj,
                                                  const int* __restrict__ idx_ji,
                                                  int* __restrict__ hist,
                                                  _Float16* __restrict__ xkt) {
    __shared__ float sbfL[32 * 42];
    __shared__ float midL[32 * 8];
    int tid = threadIdx.x;
    int row0 = blockIdx.x * 32;
    if (tid < 32) atomicAdd(&hist[idx_ji[row0 + tid]], 1);
    for (int i = tid; i < 32 * 42; i += 256)
        sbfL[i] = sbf[(size_t)row0 * 42 + i];
    __syncthreads();
    {
        int r = tid >> 3, p = tid & 7;
        float mm = 0.f;
#pragma unroll
        for (int q = 0; q < 42; ++q) mm += sbfL[r * 42 + q] * W_sbf1[q * 8 + p];
        midL[r * 8 + p] = mm;
    }
    __syncthreads();
    int r = tid >> 3;
    int c0 = (tid & 7) * 8;
    int w = row0 + r;
    int e = idx_kj[w];
    f4 sa = {}, sb = {};
#pragma unroll
    for (int p = 0; p < 8; ++p) {
        float mm = midL[r * 8 + p];
        sa += mm * *(const f4*)(W_sbf2 + (p << 6) + c0);
        sb += mm * *(const f4*)(W_sbf2 + (p << 6) + c0 + 4);
    }
    h8 xv = *(const h8*)(xke + (size_t)e * 64 + c0);
    h8 o;
#pragma unroll
    for (int u = 0; u < 4; ++u) {
        o[u]     = (_Float16)((float)xv[u]     * sa[u]);
        o[u + 4] = (_Float16)((float)xv[u + 4] * sb[u]);
    }
    *(h8*)(xkt + (size_t)w * 64 + c0) = o;
}

// ---------------------------------------------------------------------------
// CSR placement chain: hist -> block sums -> offsets -> start/next -> pos
// ---------------------------------------------------------------------------
__global__ __launch_bounds__(256) void kscan1(const int* __restrict__ hist, int* __restrict__ bsum) {
    int t = threadIdx.x;
    int w = blockIdx.x * 256 + t;
    int v = (w < E_N) ? hist[w] : 0;
#pragma unroll
    for (int off = 32; off; off >>= 1) v += __shfl_down(v, off, 64);
    __shared__ int ls[4];
    if ((t & 63) == 0) ls[t >> 6] = v;
    __syncthreads();
    if (t == 0) bsum[blockIdx.x] = ls[0] + ls[1] + ls[2] + ls[3];
}

__global__ __launch_bounds__(512) void kscan2(const int* __restrict__ bsum, int* __restrict__ boff) {
    __shared__ int s[512];
    int t = threadIdx.x;
    int v = (t < NB1) ? bsum[t] : 0;
    s[t] = v;
    __syncthreads();
    for (int off = 1; off < 512; off <<= 1) {
        int x = (t >= off) ? s[t - off] : 0;
        __syncthreads();
        s[t] += x;
        __syncthreads();
    }
    if (t < NB1) boff[t] = s[t] - v;   // exclusive
}

__global__ __launch_bounds__(256) void kscan3(const int* __restrict__ hist, const int* __restrict__ boff,
                                              int* __restrict__ start, int* __restrict__ nxt) {
    __shared__ int s[256];
    int t = threadIdx.x;
    int w = blockIdx.x * 256 + t;
    int v = (w < E_N) ? hist[w] : 0;
    s[t] = v;
    __syncthreads();
    for (int off = 1; off < 256; off <<= 1) {
        int x = (t >= off) ? s[t - off] : 0;
        __syncthreads();
        s[t] += x;
        __syncthreads();
    }
    if (w < E_N) {
        int st = boff[blockIdx.x] + s[t] - v;
        start[w] = st;
        nxt[w]   = st;
    }
}

__global__ __launch_bounds__(256) void kfill(const int* __restrict__ idx_ji,
                                             int* __restrict__ nxt, int* __restrict__ pos) {
    int w = blockIdx.x * 256 + threadIdx.x;
    if (w < T_N) pos[w] = atomicAdd(&nxt[idx_ji[w]], 1);
}

// ---------------------------------------------------------------------------
// KB3: bilinear, zero-LDS, zero-atomic, SOFTWARE-PIPELINED.
// Each j split into two c-phases of 16 MFMAs; while phase p's MFMAs run,
// phase p+1's 4 B-frags are in flight (static-parity double buffer bc[2][4]).
// tg double-buffered one jg ahead. Epilogue: non-temporal full-line stores
// to sorted slot pos[w].
// ---------------------------------------------------------------------------
__global__ __launch_bounds__(128, 3) void kb3_bilinear(const _Float16* __restrict__ xkt,
                                                       const _Float16* __restrict__ ttp,
                                                       const h8* __restrict__ wpack,
                                                       const int* __restrict__ pos,
                                                       float* __restrict__ outp) {
    int tid = threadIdx.x;
    int lane = tid & 63, wv = tid >> 6;
    int qrow = lane & 15, quad = lane >> 4;
    int row0 = blockIdx.x * 128 + wv * 64;
    int jlo = blockIdx.y * 32;

    h8 xa[4][2];
#pragma unroll
    for (int rt = 0; rt < 4; ++rt) {
        const _Float16* rp = xkt + (size_t)(row0 + rt * 16 + qrow) * 64 + quad * 8;
        xa[rt][0] = *(const h8*)rp;
        xa[rt][1] = *(const h8*)(rp + 32);
    }

    const h8* wl = wpack + lane;   // frag (j,c,nt) at index ((j*8 + c*4 + nt) << 6)

    h8 bc[2][4];
#pragma unroll
    for (int nt = 0; nt < 4; ++nt)
        bc[0][nt] = wl[((size_t)jlo * 8 + nt) << 6];          // (jlo, c=0)

    h8 tg[2][4];
#pragma unroll
    for (int rt = 0; rt < 4; ++rt)
        tg[0][rt] = *(const h8*)(ttp + (size_t)(row0 + rt * 16 + qrow) * 64 + jlo);

    f4 acc[4][4] = {};
#pragma unroll
    for (int jg = 0; jg < 4; ++jg) {
        const int tp = jg & 1;
        if (jg < 3) {
#pragma unroll
            for (int rt = 0; rt < 4; ++rt)
                tg[tp ^ 1][rt] = *(const h8*)(ttp + (size_t)(row0 + rt * 16 + qrow) * 64 + jlo + (jg + 1) * 8);
        }
#pragma unroll
        for (int ju = 0; ju < 8; ++ju) {
            const int u = jg * 8 + ju;       // 0..31 within slice
            const int j = jlo + u;

            // --- phase c=0: prefetch (j, c=1) into bc[1]; compute with bc[0]
#pragma unroll
            for (int nt = 0; nt < 4; ++nt)
                bc[1][nt] = wl[((size_t)j * 8 + 4 + nt) << 6];
#pragma unroll
            for (int rt = 0; rt < 4; ++rt) {
                _Float16 tv = tg[tp][rt][ju];
                h8 t8 = {tv, tv, tv, tv, tv, tv, tv, tv};
                h8 a0 = xa[rt][0] * t8;
#pragma unroll
                for (int nt = 0; nt < 4; ++nt)
                    acc[rt][nt] = __builtin_amdgcn_mfma_f32_16x16x32_f16(a0, bc[0][nt], acc[rt][nt], 0, 0, 0);
            }

            // --- phase c=1: prefetch (j+1, c=0) into bc[0]; compute with bc[1]
            if (u < 31) {
#pragma unroll
                for (int nt = 0; nt < 4; ++nt)
                    bc[0][nt] = wl[((size_t)(j + 1) * 8 + nt) << 6];
            }
#pragma unroll
            for (int rt = 0; rt < 4; ++rt) {
                _Float16 tv = tg[tp][rt][ju];
                h8 t8 = {tv, tv, tv, tv, tv, tv, tv, tv};
                h8 a1 = xa[rt][1] * t8;
#pragma unroll
                for (int nt = 0; nt < 4; ++nt)
                    acc[rt][nt] = __builtin_amdgcn_mfma_f32_16x16x32_f16(a1, bc[1][nt], acc[rt][nt], 0, 0, 0);
            }
        }
    }

    // C/D layout: col = lane&15, row = quad*4 + reg  (verified m89/m91)
    float* __restrict__ outh = outp + (size_t)blockIdx.y * ((size_t)T_N * 64);
#pragma unroll
    for (int rt = 0; rt < 4; ++rt) {
#pragma unroll
        for (int rr = 0; rr < 4; ++rr) {
            int w = row0 + rt * 16 + quad * 4 + rr;
            float* dst = outh + (size_t)pos[w] * 64 + qrow;
#pragma unroll
            for (int nt = 0; nt < 4; ++nt)
                __builtin_nontemporal_store(acc[rt][nt][rr], dst + nt * 16);
        }
    }
}

// ---------------------------------------------------------------------------
// KAGG (fallback path only): agg[e,:] = segment sum of outp rows.
// ---------------------------------------------------------------------------
__global__ __launch_bounds__(256) void kagg(const float* __restrict__ outp,
                                            const int* __restrict__ start,
                                            const int* __restrict__ nxt,
                                            float* __restrict__ agg) {
    int tid = threadIdx.x;
    int e = blockIdx.x * 16 + (tid >> 4);
    int c4 = (tid & 15) * 4;
    int p0 = start[e], p1 = nxt[e];
    const float* o1 = outp + (size_t)T_N * 64;
    f4 s = {0.f, 0.f, 0.f, 0.f};
    for (int p = p0; p < p1; ++p) {
        s += *(const f4*)(outp + (size_t)p * 64 + c4);
        s += *(const f4*)(o1   + (size_t)p * 64 + c4);
    }
    *(f4*)(agg + (size_t)e * 64 + c4) = s;
}

// ---------------------------------------------------------------------------
// K4 fused (primary): out = swish( segsum(outp) @ W_up ). Segment sum in the
// A-frag prologue. Only used when outp/start/nxt live in d_ws (no aliasing
// with the final out write — the R2 bug).
// ---------------------------------------------------------------------------
__global__ __launch_bounds__(256) void k4_up_fused(const float* __restrict__ outp,
                                                   const int* __restrict__ start,
                                                   const int* __restrict__ nxt,
                                                   const h8* __restrict__ wpu,
                                                   float* __restrict__ out) {
    int tid = threadIdx.x;
    int lane = tid & 63, wv = tid >> 6;
    int m = lane & 15, quad = lane >> 4;
    int rowb = blockIdx.x * 64 + wv * 16;
    int row = rowb + m;

    int p0 = start[row], p1 = nxt[row];
    const float* o1 = outp + (size_t)T_N * 64;
    f4 s0a = {}, s0b = {}, s1a = {}, s1b = {};
    for (int p = p0; p < p1; ++p) {
        const float* pr = outp + (size_t)p * 64 + quad * 8;
        s0a += *(const f4*)(pr);
        s0b += *(const f4*)(pr + 4);
        s1a += *(const f4*)(pr + 32);
        s1b += *(const f4*)(pr + 36);
        const float* qr = o1 + (size_t)p * 64 + quad * 8;
        s0a += *(const f4*)(qr);
        s0b += *(const f4*)(qr + 4);
        s1a += *(const f4*)(qr + 32);
        s1b += *(const f4*)(qr + 36);
    }

    f4 acc[16] = {};
#pragma unroll
    for (int kt = 0; kt < 2; ++kt) {
        f4 alo = kt ? s1a : s0a;
        f4 ahi = kt ? s1b : s0b;
        h8 a;
#pragma unroll
        for (int u = 0; u < 4; ++u) {
            a[u]     = (_Float16)alo[u];
            a[u + 4] = (_Float16)ahi[u];
        }
#pragma unroll
        for (int nt = 0; nt < 16; ++nt) {
            h8 b = wpu[((kt * 16 + nt) << 6) + lane];
            acc[nt] = __builtin_amdgcn_mfma_f32_16x16x32_f16(a, b, acc[nt], 0, 0, 0);
        }
    }

#pragma unroll
    for (int nt = 0; nt < 16; ++nt)
#pragma unroll
        for (int rr = 0; rr < 4; ++rr) {
            int orow = rowb + quad * 4 + rr;
            __builtin_nontemporal_store(swishf(acc[nt][rr]),
                                        out + (size_t)orow * 256 + nt * 16 + m);
        }
}

// ---------------------------------------------------------------------------
// K4 fallback: out = swish( agg @ W_up ), agg precomputed by kagg (in ws).
// ---------------------------------------------------------------------------
__global__ __launch_bounds__(256) void k4_up_agg(const float* __restrict__ agg,
                                                 const h8* __restrict__ wpu,
                                                 float* __restrict__ out) {
    int tid = threadIdx.x;
    int lane = tid & 63, wv = tid >> 6;
    int m = lane & 15, quad = lane >> 4;
    int rowb = blockIdx.x * 64 + wv * 16;

    f4 acc[16] = {};
#pragma unroll
    for (int kt = 0; kt < 2; ++kt) {
        const float* ap = agg + (size_t)(rowb + m) * 64 + kt * 32 + quad * 8;
        f4 alo = *(const f4*)ap;
        f4 ahi = *(const f4*)(ap + 4);
        h8 a;
#pragma unroll
        for (int u = 0; u < 4; ++u) {
            a[u]     = (_Float16)alo[u];
            a[u + 4] = (_Float16)ahi[u];
        }
#pragma unroll
        for (int nt = 0; nt < 16; ++nt) {
            h8 b = wpu[((kt * 16 + nt) << 6) + lane];
            acc[nt] = __builtin_amdgcn_mfma_f32_16x16x32_f16(a, b, acc[nt], 0, 0, 0);
        }
    }

#pragma unroll
    for (int nt = 0; nt < 16; ++nt)
#pragma unroll
        for (int rr = 0; rr < 4; ++rr) {
            int row = rowb + quad * 4 + rr;
            __builtin_nontemporal_store(swishf(acc[nt][rr]),
                                        out + (size_t)row * 256 + nt * 16 + m);
        }
}

// ---------------------------------------------------------------------------
extern "C" void kernel_launch(void* const* d_in, const int* in_sizes, int n_in,
                              void* d_out, int out_size, void* d_ws, size_t ws_size,
                              hipStream_t stream) {
    const float* rbf0   = (const float*)d_in[1];
    const float* sbf    = (const float*)d_in[2];
    const float* tin    = (const float*)d_in[3];
    const float* xkj    = (const float*)d_in[4];
    const int*   idx_kj = (const int*)d_in[6];
    const int*   idx_ji = (const int*)d_in[7];
    const float* W_rbf1 = (const float*)d_in[8];
    const float* W_rbf2 = (const float*)d_in[9];
    const float* W_sbf1 = (const float*)d_in[10];
    const float* W_sbf2 = (const float*)d_in[11];
    const float* W_t1   = (const float*)d_in[12];
    const float* W_down = (const float*)d_in[13];
    const float* W_up   = (const float*)d_in[14];
    const float* W_bil  = (const float*)d_in[15];

    char* ws = (char*)d_ws;
    char* ob = (char*)d_out;
    float* out = (float*)d_out;

    const size_t WS_NEED_FUSED = 53120000;   // xke+packs+outp+CSR all in ws

    if (ws_size >= WS_NEED_FUSED) {
        // ---- fused path: ALL scratch that k4 reads lives in ws (d_out is
        // only ttb/xkt, both dead before k4 writes out over them).
        _Float16* xke = (_Float16*)ws;                       // 10.24MB
        h8* wpack_bil = (h8*)(ws + 10240000);                // 512KB
        h8* wpd       = (h8*)(ws + 10764288);                // 32KB
        h8* wpt       = (h8*)(ws + 10797056);                // 40KB
        h8* wpu       = (h8*)(ws + 10838016);                // 32KB
        float* outp   = (float*)(ws + 10871808);             // 40.96MB
        int* hist  = (int*)(ws + 51831808);                  // 320KB
        int* start = (int*)(ws + 52151808);                  // 320KB
        int* nxt   = (int*)(ws + 52471808);                  // 320KB
        int* pos   = (int*)(ws + 52791808);                  // 320KB
        int* bsum  = (int*)(ws + 53111808);
        int* boff  = (int*)(ws + 53115904);
        _Float16* ttb = (_Float16*)ob;
        _Float16* xkt = (_Float16*)(ob + 10240000);

        hipMemsetAsync(hist, 0, E_N * 4, stream);
        kpack_all<<<154, 256, 0, stream>>>(W_bil, wpack_bil, W_down, wpd, W_t1, wpt, W_up, wpu);
        k1_down<<<625, 256, 0, stream>>>(rbf0, xkj, W_rbf1, W_rbf2, wpd, xke);
        kb1_tproj<<<625, 256, 0, stream>>>(tin, wpt, ttb);
        kb2_gather<<<2500, 256, 0, stream>>>(sbf, W_sbf1, W_sbf2, xke, idx_kj, idx_ji, hist, xkt);
        kscan1<<<NB1, 256, 0, stream>>>(hist, bsum);
        kscan2<<<1, 512, 0, stream>>>(bsum, boff);
        kscan3<<<NB1, 256, 0, stream>>>(hist, boff, start, nxt);
        kfill<<<NB1, 256, 0, stream>>>(idx_ji, nxt, pos);
        kb3_bilinear<<<dim3(625, 2), 128, 0, stream>>>(xkt, ttb, wpack_bil, pos, outp);
        k4_up_fused<<<1250, 256, 0, stream>>>(outp, start, nxt, wpu, out);
    } else {
        // ---- fallback (R1-proven layout): agg staged in ws, outp/CSR in
        // d_out, separate kagg consumes outp before k4 overwrites d_out.
        _Float16* xke = (_Float16*)ws;
        float*    agg = (float*)(ws + 10240000);
        h8* wpack_bil = (h8*)(ws + 30720000);
        h8* wpd       = (h8*)(ws + 31244288);
        h8* wpt       = (h8*)(ws + 31277056);
        h8* wpu       = (h8*)(ws + 31318016);
        _Float16* ttb  = (_Float16*)ob;
        _Float16* xkt  = (_Float16*)(ob + 10240000);
        float*    outp = (float*)(ob + 20480000);
        int* hist  = (int*)(ob + 61440000);
        int* start = (int*)(ob + 61760000);
        int* nxt   = (int*)(ob + 62080000);
        int* pos   = (int*)(ob + 62400000);
        int* bsum  = (int*)(ob + 62720000);
        int* boff  = (int*)(ob + 62724096);

        hipMemsetAsync(hist, 0, E_N * 4, stream);
        kpack_all<<<154, 256, 0, stream>>>(W_bil, wpack_bil, W_down, wpd, W_t1, wpt, W_up, wpu);
        k1_down<<<625, 256, 0, stream>>>(rbf0, xkj, W_rbf1, W_rbf2, wpd, xke);
        kb1_tproj<<<625, 256, 0, stream>>>(tin, wpt, ttb);
        kb2_gather<<<2500, 256, 0, stream>>>(sbf, W_sbf1, W_sbf2, xke, idx_kj, idx_ji, hist, xkt);
        kscan1<<<NB1, 256, 0, stream>>>(hist, bsum);
        kscan2<<<1, 512, 0, stream>>>(bsum, boff);
        kscan3<<<NB1, 256, 0, stream>>>(hist, boff, start, nxt);
        kfill<<<NB1, 256, 0, stream>>>(idx_ji, nxt, pos);
        kb3_bilinear<<<dim3(625, 2), 128, 0, stream>>>(xkt, ttb, wpack_bil, pos, outp);
        kagg<<<5000, 256, 0, stream>>>(outp, start, nxt, agg);
        k4_up_agg<<<1250, 256, 0, stream>>>(agg, wpu, out);
    }
}